// Round 14
// baseline (100.122 us; speedup 1.0000x reference)
//
#include <hip/hip_runtime.h>
#include <hip/hip_cooperative_groups.h>
#include <math.h>

namespace cg = cooperative_groups;

constexpr int IMG = 224;
constexpr int Bb  = 16;
constexpr int Vv  = 8;
constexpr int Nn  = 8192;
constexpr int Mm  = 1024;
constexpr int G   = 32;                 // bins per axis
constexpr float Hh = 1.0f / 32.0f;      // cell size, normalized coords

// ---- shared device helpers (identical math in both kernels) --------------

__device__ __forceinline__ void search_and_emit(
    const float4* __restrict__ s_e, const int* __restrict__ s_start,
    int q0, int q1, float zq,
    const float* __restrict__ bnd, const float* __restrict__ ip,
    float* __restrict__ out, size_t ob)
{
    float ox = (float)q0 / (float)IMG;
    float oy = (float)q1 / (float)IMG;
    float o2 = __fadd_rn(__fmul_rn(ox, ox), __fmul_rn(oy, oy));
    // exact power-of-2 scale; d2 bits identical to prior rounds
    float n2ox = __fmul_rn(-2.0f, ox);
    float n2oy = __fmul_rn(-2.0f, oy);

    int cx = min(G - 1, max(0, (int)(ox * (float)G)));
    int cy = min(G - 1, max(0, (int)(oy * (float)G)));

    float best = INFINITY;
    int   bj   = 0;

    // tier 1: full 5x5 window as 5 contiguous row-ranges, flattened
    int x0 = max(cx - 2, 0), x1 = min(cx + 2, G - 1);
    int bases[5], offs[5];
    int T = 0;
    #pragma unroll
    for (int r = 0; r < 5; ++r) {
        int yy = cy - 2 + r;
        int bb = 0, LL = 0;
        if (yy >= 0 && yy < G) {
            int rowb = yy * G;
            int e0 = s_start[rowb + x0];
            int e1 = s_start[rowb + x1 + 1];
            bb = e0; LL = e1 - e0;
        }
        bases[r] = bb; offs[r] = T; T += LL;
    }
    for (int u = 0; u < T; ++u) {
        int base2 = bases[0], off2 = offs[0];
        #pragma unroll
        for (int r = 1; r < 5; ++r) {              // static unroll -> registers
            bool in = (u >= offs[r]);
            base2 = in ? bases[r] : base2;
            off2  = in ? offs[r]  : off2;
        }
        float4 cd = s_e[base2 + (u - off2)];
        float dn = __fadd_rn(__fmul_rn(n2ox, cd.x), __fmul_rn(n2oy, cd.y));
        float d2 = __fadd_rn(__fadd_rn(o2, cd.z), dn);
        int   j  = __float_as_int(cd.w);
        bool better = (d2 < best) || (d2 == best && j < bj);
        best = better ? d2 : best;
        bj   = better ? j  : bj;
    }

    // tier 2 (P~3e-6): serial ring walker, rings >= 3.
    if (!(best < 4.0f * Hh * Hh - 1e-5f)) {
        for (int r = 3; r <= G; ++r) {
            float lim = (float)(r - 1) * Hh;
            if (best < lim * lim - 1e-5f) break;
            int rx0 = max(0, cx - r), rx1 = min(G - 1, cx + r);
            int ry0 = max(0, cy - r), ry1 = min(G - 1, cy + r);
            for (int yy = ry0; yy <= ry1; ++yy) {
                bool yedge = (yy == cy - r) || (yy == cy + r);
                for (int xx = rx0; xx <= rx1; ++xx) {
                    if (!yedge && xx != cx - r && xx != cx + r) continue;
                    int c = yy * G + xx;
                    int e0 = s_start[c], e1 = s_start[c + 1];
                    for (int e = e0; e < e1; ++e) {
                        float4 cd = s_e[e];
                        float dn = __fadd_rn(__fmul_rn(n2ox, cd.x), __fmul_rn(n2oy, cd.y));
                        float d2 = __fadd_rn(__fadd_rn(o2, cd.z), dn);
                        int   j  = __float_as_int(cd.w);
                        bool better = (d2 < best) || (d2 == best && j < bj);
                        best = better ? d2 : best;
                        bj   = better ? j  : bj;
                    }
                }
            }
        }
    }

    float nbx = bnd[2 * bj];
    float nby = bnd[2 * bj + 1];
    float h0 = nbx * zq, h1 = nby * zq;
    float r0 = h0 * ip[0] + h1 * ip[4] + zq * ip[8]  + ip[12];
    float r1 = h0 * ip[1] + h1 * ip[5] + zq * ip[9]  + ip[13];
    float r2 = h0 * ip[2] + h1 * ip[6] + zq * ip[10] + ip[14];
    out[ob]     = r0;
    out[ob + 1] = r1;
    out[ob + 2] = r2;
}

// ---- cooperative kernel: 16 producer blocks bin -> grid sync -> all search
__global__ __launch_bounds__(256) void calib_coop(
    const float* __restrict__ pc, const float* __restrict__ mask,
    const float* __restrict__ bounds, const float* __restrict__ inv_param,
    const float* __restrict__ proj_fine, const float* __restrict__ proj_finez,
    const int* __restrict__ view_p,
    float4* __restrict__ ws_e, int* __restrict__ ws_s,
    float* __restrict__ out)
{
    const int view = *view_p;
    const int b = blockIdx.y;
    const int t = threadIdx.x;
    const int lane = t & 63;
    const int w = t >> 6;

    __shared__ float4 s_e[Mm];
    __shared__ int s_start[1025];
    __shared__ int s_cnt[1024];
    __shared__ int s_wtot[4];

    // early-issue per-point loads (all blocks; hide under phase A)
    const int ipt = blockIdx.x * 256 + t;
    const size_t pf = (size_t)(b * Vv + view) * Nn + ipt;
    float2 pxy = reinterpret_cast<const float2*>(proj_fine)[pf];
    float z    = proj_finez[pf];
    const size_t ob = ((size_t)b * Nn + ipt) * 3;
    float pc0 = pc[ob], pc1 = pc[ob + 1], pc2 = pc[ob + 2];

    int i0 = (int)rintf(pxy.x);                   // round half-to-even
    int i1 = (int)rintf((float)IMG - pxy.y);
    int xi = min(max(i1 + 1, 0), IMG + 1);
    int yi = min(max(i0 + 1, 0), IMG + 1);
    float mval = 0.0f;
    if (xi >= 1 && xi <= IMG && yi >= 1 && yi <= IMG)
        mval = mask[((size_t)(b * Vv + view) * IMG + (xi - 1)) * IMG + (yi - 1)];
    const bool use_back = (mval == 0.0f);

    const float* bnd = bounds + (size_t)(b * Vv + view) * Mm * 2;
    const bool producer = (blockIdx.x == 0);

    if (producer) {
        // ---- bin batch b into LDS, then publish to ws -------------------
        #pragma unroll
        for (int u = 0; u < 4; ++u) s_cnt[t + 256 * u] = 0;
        __syncthreads();

        float bdx[4], bdy[4];
        int cell[4];
        #pragma unroll
        for (int u = 0; u < 4; ++u) {
            int j = t + 256 * u;
            float2 bxy = reinterpret_cast<const float2*>(bnd)[j];
            bdx[u] = bxy.x / (float)IMG;          // exact IEEE div, matches ref
            bdy[u] = bxy.y / (float)IMG;
            int cx = min(G - 1, max(0, (int)(bdx[u] * (float)G)));
            int cy = min(G - 1, max(0, (int)(bdy[u] * (float)G)));
            cell[u] = cy * G + cx;
            atomicAdd(&s_cnt[cell[u]], 1);
        }
        __syncthreads();

        int c0 = s_cnt[4 * t], c1 = s_cnt[4 * t + 1];
        int c2 = s_cnt[4 * t + 2], c3 = s_cnt[4 * t + 3];
        int psum = c0 + c1 + c2 + c3;
        int incl = psum;
        #pragma unroll
        for (int off = 1; off < 64; off <<= 1) {
            int v = __shfl_up(incl, off);
            if (lane >= off) incl += v;
        }
        if (lane == 63) s_wtot[w] = incl;
        __syncthreads();
        int basew = 0;
        for (int ww = 0; ww < w; ++ww) basew += s_wtot[ww];
        int base = basew + incl - psum;
        s_start[4 * t] = base; s_start[4 * t + 1] = base + c0;
        s_start[4 * t + 2] = base + c0 + c1; s_start[4 * t + 3] = base + c0 + c1 + c2;
        if (t == 0) s_start[1024] = Mm;
        s_cnt[4 * t] = base; s_cnt[4 * t + 1] = base + c0;
        s_cnt[4 * t + 2] = base + c0 + c1; s_cnt[4 * t + 3] = base + c0 + c1 + c2;
        __syncthreads();

        #pragma unroll
        for (int u = 0; u < 4; ++u) {
            int j = t + 256 * u;
            int pos = atomicAdd(&s_cnt[cell[u]], 1);
            float nrm = __fadd_rn(__fmul_rn(bdx[u], bdx[u]), __fmul_rn(bdy[u], bdy[u]));
            s_e[pos] = make_float4(bdx[u], bdy[u], nrm, __int_as_float(j));
        }
        __syncthreads();

        // publish table + starts (intra-cell order atomic-arbitrary; final
        // lex (d2,j) result is order-invariant => deterministic output)
        float4* we = ws_e + (size_t)b * Mm;
        #pragma unroll
        for (int u = 0; u < 4; ++u) we[t + 256 * u] = s_e[t + 256 * u];
        int* wss = ws_s + (size_t)b * 1025;
        for (int c = t; c < 1025; c += 256) wss[c] = s_start[c];
    }

    // passthrough writes before the sync (independent of the table)
    if (!use_back) {
        out[ob]     = pc0;
        out[ob + 1] = pc1;
        out[ob + 2] = pc2;
    }

    cg::this_grid().sync();

    if (!producer) {
        // cheap copy: table + starts from L2 (no atomics, no scan)
        const float4* we = ws_e + (size_t)b * Mm;
        #pragma unroll
        for (int u = 0; u < 4; ++u) s_e[t + 256 * u] = we[t + 256 * u];
        const int* wss = ws_s + (size_t)b * 1025;
        for (int c = t; c < 1025; c += 256) s_start[c] = wss[c];
        __syncthreads();
    }

    if (use_back) {
        const float* ip = inv_param + (size_t)(b * Vv + view) * 16;
        search_and_emit(s_e, s_start, i0, i1, z, bnd, ip, out, ob);
    }
}

// ---- fallback: R10 fused kernel (known-good, ~19 us) ---------------------
__global__ __launch_bounds__(256) void calib_fused(
    const float* __restrict__ pc, const float* __restrict__ mask,
    const float* __restrict__ bounds, const float* __restrict__ inv_param,
    const float* __restrict__ proj_fine, const float* __restrict__ proj_finez,
    const int* __restrict__ view_p, float* __restrict__ out)
{
    const int view = *view_p;
    const int b = blockIdx.y;
    const int t = threadIdx.x;
    const int lane = t & 63;
    const int w = t >> 6;

    __shared__ float4 s_e[Mm];
    __shared__ int s_start[1025];
    __shared__ int s_cnt[1024];
    __shared__ int s_wtot[4];

    const int ipt = blockIdx.x * 256 + t;
    const size_t pf = (size_t)(b * Vv + view) * Nn + ipt;
    float2 pxy = reinterpret_cast<const float2*>(proj_fine)[pf];
    float z    = proj_finez[pf];
    const size_t ob = ((size_t)b * Nn + ipt) * 3;
    float pc0 = pc[ob], pc1 = pc[ob + 1], pc2 = pc[ob + 2];

    int i0 = (int)rintf(pxy.x);
    int i1 = (int)rintf((float)IMG - pxy.y);
    int xi = min(max(i1 + 1, 0), IMG + 1);
    int yi = min(max(i0 + 1, 0), IMG + 1);
    float mval = 0.0f;
    if (xi >= 1 && xi <= IMG && yi >= 1 && yi <= IMG)
        mval = mask[((size_t)(b * Vv + view) * IMG + (xi - 1)) * IMG + (yi - 1)];
    const bool use_back = (mval == 0.0f);

    #pragma unroll
    for (int u = 0; u < 4; ++u) s_cnt[t + 256 * u] = 0;
    __syncthreads();

    const float* bnd = bounds + (size_t)(b * Vv + view) * Mm * 2;
    float bdx[4], bdy[4];
    int cell[4];
    #pragma unroll
    for (int u = 0; u < 4; ++u) {
        int j = t + 256 * u;
        float2 bxy = reinterpret_cast<const float2*>(bnd)[j];
        bdx[u] = bxy.x / (float)IMG;
        bdy[u] = bxy.y / (float)IMG;
        int cx = min(G - 1, max(0, (int)(bdx[u] * (float)G)));
        int cy = min(G - 1, max(0, (int)(bdy[u] * (float)G)));
        cell[u] = cy * G + cx;
        atomicAdd(&s_cnt[cell[u]], 1);
    }
    __syncthreads();

    int c0 = s_cnt[4 * t], c1 = s_cnt[4 * t + 1];
    int c2 = s_cnt[4 * t + 2], c3 = s_cnt[4 * t + 3];
    int psum = c0 + c1 + c2 + c3;
    int incl = psum;
    #pragma unroll
    for (int off = 1; off < 64; off <<= 1) {
        int v = __shfl_up(incl, off);
        if (lane >= off) incl += v;
    }
    if (lane == 63) s_wtot[w] = incl;
    __syncthreads();
    int basew = 0;
    for (int ww = 0; ww < w; ++ww) basew += s_wtot[ww];
    int base = basew + incl - psum;
    s_start[4 * t] = base; s_start[4 * t + 1] = base + c0;
    s_start[4 * t + 2] = base + c0 + c1; s_start[4 * t + 3] = base + c0 + c1 + c2;
    if (t == 0) s_start[1024] = Mm;
    s_cnt[4 * t] = base; s_cnt[4 * t + 1] = base + c0;
    s_cnt[4 * t + 2] = base + c0 + c1; s_cnt[4 * t + 3] = base + c0 + c1 + c2;
    __syncthreads();

    #pragma unroll
    for (int u = 0; u < 4; ++u) {
        int j = t + 256 * u;
        int pos = atomicAdd(&s_cnt[cell[u]], 1);
        float nrm = __fadd_rn(__fmul_rn(bdx[u], bdx[u]), __fmul_rn(bdy[u], bdy[u]));
        s_e[pos] = make_float4(bdx[u], bdy[u], nrm, __int_as_float(j));
    }
    __syncthreads();

    if (use_back) {
        const float* ip = inv_param + (size_t)(b * Vv + view) * 16;
        search_and_emit(s_e, s_start, i0, i1, z, bnd, ip, out, ob);
    } else {
        out[ob]     = pc0;
        out[ob + 1] = pc1;
        out[ob + 2] = pc2;
    }
}

extern "C" void kernel_launch(void* const* d_in, const int* in_sizes, int n_in,
                              void* d_out, int out_size, void* d_ws, size_t ws_size,
                              hipStream_t stream) {
    const float* pc         = (const float*)d_in[0];
    const float* mask       = (const float*)d_in[1];
    const float* bounds     = (const float*)d_in[2];
    const float* inv_param  = (const float*)d_in[3];
    const float* proj_fine  = (const float*)d_in[4];
    const float* proj_finez = (const float*)d_in[5];
    const int*   view_p     = (const int*)d_in[6];
    float* out = (float*)d_out;

    const size_t ws_need = (size_t)Bb * Mm * sizeof(float4)
                         + (size_t)Bb * 1025 * sizeof(int);
    dim3 grid(Nn / 256, Bb);

    if (ws_size >= ws_need) {
        float4* ws_e = (float4*)d_ws;
        int*    ws_s = (int*)((char*)d_ws + (size_t)Bb * Mm * sizeof(float4));
        void* args[10] = {
            (void*)&pc, (void*)&mask, (void*)&bounds, (void*)&inv_param,
            (void*)&proj_fine, (void*)&proj_finez, (void*)&view_p,
            (void*)&ws_e, (void*)&ws_s, (void*)&out };
        hipError_t e = hipLaunchCooperativeKernel(
            (const void*)calib_coop, grid, dim3(256), args, 0, stream);
        if (e == hipSuccess) return;
        (void)hipGetLastError();                  // clear, fall through
    }
    calib_fused<<<grid, 256, 0, stream>>>(pc, mask, bounds, inv_param,
                                          proj_fine, proj_finez, view_p, out);
}

// Round 15
// 25.838 us; speedup vs baseline: 3.8750x; 3.8750x over previous
//
#include <hip/hip_runtime.h>
#include <math.h>

constexpr int IMG = 224;
constexpr int Bb  = 16;
constexpr int Vv  = 8;
constexpr int Nn  = 8192;
constexpr int Mm  = 1024;
constexpr int G   = 32;                 // bins per axis
constexpr float Hh = 1.0f / 32.0f;      // cell size, normalized coords
constexpr int CAP = 4;                  // slots per cell (Poisson(1): P(>4)=0.004)
constexpr int OVF = 192;                // overflow list capacity (avg ~4 used)

// Single fused kernel, 512 blocks (2/CU) x 256 threads, 256 points/block.
// Binning: single-pass fixed-capacity cells (1 atomic/cand, no scan, 2
// barriers). Rare over-capacity candidates go to an overflow list that every
// query scans in full (superset-of-window => result invariant, exact).
__global__ __launch_bounds__(256) void calib_kernel(
    const float* __restrict__ pc,         // (B, N, 3)
    const float* __restrict__ mask,       // (B, V, IMG, IMG)
    const float* __restrict__ bounds,     // (B, V, M, 2)
    const float* __restrict__ inv_param,  // (B, V, 4, 4)
    const float* __restrict__ proj_fine,  // (B, V, N, 2)
    const float* __restrict__ proj_finez, // (B, V, N)
    const int*   __restrict__ view_p,
    float*       __restrict__ out)        // (B, N, 3)
{
    const int view = *view_p;
    const int b = blockIdx.y;
    const int t = threadIdx.x;

    __shared__ float2 s_xy[Mm * CAP];     // (bdx, bdy) per slot   32 KB
    __shared__ unsigned short s_j[Mm * CAP]; // candidate index     8 KB
    __shared__ int s_cnt[Mm];             // per-cell counters      4 KB
    __shared__ float2 s_oxy[OVF];         // overflow entries       1.5 KB
    __shared__ unsigned short s_oj[OVF];
    __shared__ int s_ocnt;

    // ---- early-issue all global loads (hide latency under binning) -------
    const float* bnd = bounds + (size_t)(b * Vv + view) * Mm * 2;
    float2 bxy0 = reinterpret_cast<const float2*>(bnd)[t];
    float2 bxy1 = reinterpret_cast<const float2*>(bnd)[t + 256];
    float2 bxy2 = reinterpret_cast<const float2*>(bnd)[t + 512];
    float2 bxy3 = reinterpret_cast<const float2*>(bnd)[t + 768];

    const int ipt = blockIdx.x * 256 + t;
    const size_t pf = (size_t)(b * Vv + view) * Nn + ipt;
    float2 pxy = reinterpret_cast<const float2*>(proj_fine)[pf];
    float z    = proj_finez[pf];
    const size_t ob = ((size_t)b * Nn + ipt) * 3;
    float pc0 = pc[ob], pc1 = pc[ob + 1], pc2 = pc[ob + 2];

    // zero counters
    if (t == 0) s_ocnt = 0;
    #pragma unroll
    for (int u = 0; u < 4; ++u) s_cnt[t + 256 * u] = 0;

    // mask probe (pxy chain) issued pre-barrier; hides under binning
    int i0 = (int)rintf(pxy.x);                   // round half-to-even
    int i1 = (int)rintf((float)IMG - pxy.y);
    int xi = min(max(i1 + 1, 0), IMG + 1);
    int yi = min(max(i0 + 1, 0), IMG + 1);
    float mval = 0.0f;
    if (xi >= 1 && xi <= IMG && yi >= 1 && yi <= IMG)
        mval = mask[((size_t)(b * Vv + view) * IMG + (xi - 1)) * IMG + (yi - 1)];
    const bool use_back = (mval == 0.0f);

    __syncthreads();                               // counters zeroed

    // ---- single-pass binning (1 atomic per candidate, no scan) -----------
    {
        float2 ba[4] = {bxy0, bxy1, bxy2, bxy3};
        #pragma unroll
        for (int u = 0; u < 4; ++u) {
            int j = t + 256 * u;
            float bdx = ba[u].x / (float)IMG;     // exact IEEE div, matches ref
            float bdy = ba[u].y / (float)IMG;
            int cx = min(G - 1, max(0, (int)(bdx * (float)G)));
            int cy = min(G - 1, max(0, (int)(bdy * (float)G)));
            int c  = cy * G + cx;
            int slot = atomicAdd(&s_cnt[c], 1);
            if (slot < CAP) {
                s_xy[c * CAP + slot] = make_float2(bdx, bdy);
                s_j [c * CAP + slot] = (unsigned short)j;
            } else {
                int op = atomicAdd(&s_ocnt, 1);   // rare (P~0.004/cell)
                s_oxy[op] = make_float2(bdx, bdy);
                s_oj [op] = (unsigned short)j;
            }
        }
    }

    // passthrough writes overlap the binning tail
    if (!use_back) {
        out[ob]     = pc0;
        out[ob + 1] = pc1;
        out[ob + 2] = pc2;
    }
    __syncthreads();                               // table ready

    if (!use_back) return;

    // ---------------- search: 5x5 window + overflow + ring walker ---------
    float ox = (float)i0 / (float)IMG;
    float oy = (float)i1 / (float)IMG;
    float o2 = __fadd_rn(__fmul_rn(ox, ox), __fmul_rn(oy, oy));
    // exact power-of-2 scale; d2 bits identical to prior rounds
    float n2ox = __fmul_rn(-2.0f, ox);
    float n2oy = __fmul_rn(-2.0f, oy);

    int cx = min(G - 1, max(0, (int)(ox * (float)G)));
    int cy = min(G - 1, max(0, (int)(oy * (float)G)));

    float best = INFINITY;
    int   bj   = 0;

    // nrm recomputed with the identical ops => d2 bits frozen
    #define EVAL_SLOT(XY, JJ)                                               \
    {                                                                       \
        float bdx_ = (XY).x, bdy_ = (XY).y;                                 \
        float nrm_ = __fadd_rn(__fmul_rn(bdx_, bdx_), __fmul_rn(bdy_, bdy_)); \
        float dn_  = __fadd_rn(__fmul_rn(n2ox, bdx_), __fmul_rn(n2oy, bdy_)); \
        float d2_  = __fadd_rn(__fadd_rn(o2, nrm_), dn_);                   \
        int   j_   = (int)(JJ);                                             \
        bool better_ = (d2_ < best) || (d2_ == best && j_ < bj);            \
        best = better_ ? d2_ : best;                                        \
        bj   = better_ ? j_  : bj;                                          \
    }

    // tier 1: 5x5 window, fixed-capacity cells
    {
        int x0 = max(cx - 2, 0), x1 = min(cx + 2, G - 1);
        int y0 = max(cy - 2, 0), y1 = min(cy + 2, G - 1);
        for (int yy = y0; yy <= y1; ++yy) {
            for (int xx = x0; xx <= x1; ++xx) {
                int c = yy * G + xx;
                int n = min(s_cnt[c], CAP);
                int bs = c * CAP;
                for (int s = 0; s < n; ++s) EVAL_SLOT(s_xy[bs + s], s_j[bs + s]);
            }
        }
    }
    // overflow list: scanned in full by every query (superset-safe, exact)
    {
        int on = s_ocnt;
        for (int e = 0; e < on; ++e) EVAL_SLOT(s_oxy[e], s_oj[e]);
    }

    // tier 2 (P~3e-6): serial ring walker, rings >= 3.
    // visited superset of rings<=2 => unvisited d2 >= 4h^2 - slop
    if (!(best < 4.0f * Hh * Hh - 1e-5f)) {
        for (int r = 3; r <= G; ++r) {
            float lim = (float)(r - 1) * Hh;
            if (best < lim * lim - 1e-5f) break;
            int rx0 = max(0, cx - r), rx1 = min(G - 1, cx + r);
            int ry0 = max(0, cy - r), ry1 = min(G - 1, cy + r);
            for (int yy = ry0; yy <= ry1; ++yy) {
                bool yedge = (yy == cy - r) || (yy == cy + r);
                for (int xx = rx0; xx <= rx1; ++xx) {
                    if (!yedge && xx != cx - r && xx != cx + r) continue;
                    int c = yy * G + xx;
                    int n = min(s_cnt[c], CAP);
                    int bs = c * CAP;
                    for (int s = 0; s < n; ++s) EVAL_SLOT(s_xy[bs + s], s_j[bs + s]);
                }
            }
        }
    }
    #undef EVAL_SLOT

    // back-projection: [nbx*z, nby*z, z, 1] @ inv_param[b, view][:, 0:3]
    float nbx = bnd[2 * bj];
    float nby = bnd[2 * bj + 1];
    const float* ip = inv_param + (size_t)(b * Vv + view) * 16;
    float h0 = nbx * z, h1 = nby * z;
    float r0 = h0 * ip[0] + h1 * ip[4] + z * ip[8]  + ip[12];
    float r1 = h0 * ip[1] + h1 * ip[5] + z * ip[9]  + ip[13];
    float r2 = h0 * ip[2] + h1 * ip[6] + z * ip[10] + ip[14];
    out[ob]     = r0;
    out[ob + 1] = r1;
    out[ob + 2] = r2;
}

extern "C" void kernel_launch(void* const* d_in, const int* in_sizes, int n_in,
                              void* d_out, int out_size, void* d_ws, size_t ws_size,
                              hipStream_t stream) {
    const float* pc         = (const float*)d_in[0];
    const float* mask       = (const float*)d_in[1];
    const float* bounds     = (const float*)d_in[2];
    const float* inv_param  = (const float*)d_in[3];
    const float* proj_fine  = (const float*)d_in[4];
    const float* proj_finez = (const float*)d_in[5];
    const int*   view_p     = (const int*)d_in[6];
    float* out = (float*)d_out;

    dim3 grid(Nn / 256, Bb);              // 512 blocks = 2/CU, one launch
    calib_kernel<<<grid, 256, 0, stream>>>(pc, mask, bounds, inv_param,
                                           proj_fine, proj_finez, view_p, out);
}

// Round 16
// 19.008 us; speedup vs baseline: 5.2674x; 1.3593x over previous
//
#include <hip/hip_runtime.h>
#include <math.h>

constexpr int IMG = 224;
constexpr int Bb  = 16;
constexpr int Vv  = 8;
constexpr int Nn  = 8192;
constexpr int Mm  = 1024;
constexpr int G   = 32;                 // bins per axis
constexpr float Hh = 1.0f / 32.0f;      // cell size, normalized coords

// Single fused kernel (512 blocks = 2/CU): per-block binning of its batch
// (redundant across the 32 chunks of a batch, ~1 us total) + per-thread
// grid-pruned NN search. No workspace, one launch, no cross-block deps.
// Best-measured configuration (R10: 19.05 us); R11-R15 structural variants
// all regressed or were neutral.
__global__ __launch_bounds__(256) void calib_kernel(
    const float* __restrict__ pc,         // (B, N, 3)
    const float* __restrict__ mask,       // (B, V, IMG, IMG)
    const float* __restrict__ bounds,     // (B, V, M, 2)
    const float* __restrict__ inv_param,  // (B, V, 4, 4)
    const float* __restrict__ proj_fine,  // (B, V, N, 2)
    const float* __restrict__ proj_finez, // (B, V, N)
    const int*   __restrict__ view_p,
    float*       __restrict__ out)        // (B, N, 3)
{
    const int view = *view_p;
    const int b = blockIdx.y;
    const int t = threadIdx.x;
    const int lane = t & 63;
    const int w = t >> 6;

    __shared__ float4 s_e[Mm];            // packed (bdx, bdy, |bd|^2, j)
    __shared__ int s_start[1025];         // cell -> range start
    __shared__ int s_cnt[1024];           // counts, then cursors
    __shared__ int s_wtot[4];

    // ---------------- phase 1: bin this batch's candidates ----------------
    #pragma unroll
    for (int u = 0; u < 4; ++u) s_cnt[t + 256 * u] = 0;
    __syncthreads();

    const float* bnd = bounds + (size_t)(b * Vv + view) * Mm * 2;
    float bdx[4], bdy[4];
    int cell[4];
    #pragma unroll
    for (int u = 0; u < 4; ++u) {
        int j = t + 256 * u;
        float2 bxy = reinterpret_cast<const float2*>(bnd)[j];
        bdx[u] = bxy.x / (float)IMG;      // exact IEEE div, matches ref
        bdy[u] = bxy.y / (float)IMG;
        int cx = min(G - 1, max(0, (int)(bdx[u] * (float)G)));
        int cy = min(G - 1, max(0, (int)(bdy[u] * (float)G)));
        cell[u] = cy * G + cx;
        atomicAdd(&s_cnt[cell[u]], 1);
    }
    __syncthreads();

    // prefix sum over 1024 cells: 4 serial/thread + wave shfl-scan + fixup
    int c0 = s_cnt[4 * t], c1 = s_cnt[4 * t + 1];
    int c2 = s_cnt[4 * t + 2], c3 = s_cnt[4 * t + 3];
    int psum = c0 + c1 + c2 + c3;
    int incl = psum;
    #pragma unroll
    for (int off = 1; off < 64; off <<= 1) {
        int v = __shfl_up(incl, off);
        if (lane >= off) incl += v;
    }
    if (lane == 63) s_wtot[w] = incl;
    __syncthreads();
    int basew = 0;
    for (int ww = 0; ww < w; ++ww) basew += s_wtot[ww];
    int base = basew + incl - psum;       // exclusive start of cell 4t
    s_start[4 * t] = base; s_start[4 * t + 1] = base + c0;
    s_start[4 * t + 2] = base + c0 + c1; s_start[4 * t + 3] = base + c0 + c1 + c2;
    if (t == 0) s_start[1024] = Mm;
    s_cnt[4 * t] = base; s_cnt[4 * t + 1] = base + c0;
    s_cnt[4 * t + 2] = base + c0 + c1; s_cnt[4 * t + 3] = base + c0 + c1 + c2;
    __syncthreads();

    // scatter (intra-cell order atomic-arbitrary; lex (d2,j) reduction makes
    // the final result order-invariant => deterministic output)
    #pragma unroll
    for (int u = 0; u < 4; ++u) {
        int j = t + 256 * u;
        int pos = atomicAdd(&s_cnt[cell[u]], 1);
        float nrm = __fadd_rn(__fmul_rn(bdx[u], bdx[u]), __fmul_rn(bdy[u], bdy[u]));
        s_e[pos] = make_float4(bdx[u], bdy[u], nrm, __int_as_float(j));
    }
    __syncthreads();

    // ---------------- phase 2: one thread = one point ----------------------
    const int i = blockIdx.x * 256 + t;
    const size_t pf = (size_t)(b * Vv + view) * Nn + i;
    float2 pxy = reinterpret_cast<const float2*>(proj_fine)[pf];

    int i0 = (int)rintf(pxy.x);                 // round half-to-even
    int i1 = (int)rintf((float)IMG - pxy.y);

    // padded-mask probe
    int xi = min(max(i1 + 1, 0), IMG + 1);
    int yi = min(max(i0 + 1, 0), IMG + 1);
    float mval = 0.0f;
    if (xi >= 1 && xi <= IMG && yi >= 1 && yi <= IMG)
        mval = mask[((size_t)(b * Vv + view) * IMG + (xi - 1)) * IMG + (yi - 1)];
    const bool use_back = (mval == 0.0f);

    const size_t ob = ((size_t)b * Nn + i) * 3;
    if (use_back) {
        float ox = (float)i0 / (float)IMG;
        float oy = (float)i1 / (float)IMG;
        float o2 = __fadd_rn(__fmul_rn(ox, ox), __fmul_rn(oy, oy));
        // exact power-of-2 scale; d2 bits identical to prior rounds
        float n2ox = __fmul_rn(-2.0f, ox);
        float n2oy = __fmul_rn(-2.0f, oy);

        int cx = min(G - 1, max(0, (int)(ox * (float)G)));
        int cy = min(G - 1, max(0, (int)(oy * (float)G)));

        float best = INFINITY;
        int   bj   = 0;

        // tier 1: full 5x5 window, serial per thread (visit order irrelevant)
        int x0 = max(cx - 2, 0), x1 = min(cx + 2, G - 1);
        int y0 = max(cy - 2, 0), y1 = min(cy + 2, G - 1);
        for (int yy = y0; yy <= y1; ++yy) {
            int rowb = yy * G;
            int e0 = s_start[rowb + x0];
            int e1 = s_start[rowb + x1 + 1];
            for (int e = e0; e < e1; ++e) {
                float4 cd = s_e[e];
                float dn = __fadd_rn(__fmul_rn(n2ox, cd.x), __fmul_rn(n2oy, cd.y));
                float d2 = __fadd_rn(__fadd_rn(o2, cd.z), dn);
                int   j  = __float_as_int(cd.w);
                bool better = (d2 < best) || (d2 == best && j < bj);
                best = better ? d2 : best;
                bj   = better ? j  : bj;
            }
        }

        // tier 2 (P~3e-6): serial ring walker, rings >= 3.
        // unvisited = Chebyshev cell-ring >= 3 => d >= 2h => d2 >= 4h^2-slop
        if (!(best < 4.0f * Hh * Hh - 1e-5f)) {
            for (int r = 3; r <= G; ++r) {
                float lim = (float)(r - 1) * Hh;
                if (best < lim * lim - 1e-5f) break;
                int rx0 = max(0, cx - r), rx1 = min(G - 1, cx + r);
                int ry0 = max(0, cy - r), ry1 = min(G - 1, cy + r);
                for (int yy = ry0; yy <= ry1; ++yy) {
                    bool yedge = (yy == cy - r) || (yy == cy + r);
                    for (int xx = rx0; xx <= rx1; ++xx) {
                        if (!yedge && xx != cx - r && xx != cx + r) continue;
                        int c = yy * G + xx;
                        int e0 = s_start[c], e1 = s_start[c + 1];
                        for (int e = e0; e < e1; ++e) {
                            float4 cd = s_e[e];
                            float dn = __fadd_rn(__fmul_rn(n2ox, cd.x), __fmul_rn(n2oy, cd.y));
                            float d2 = __fadd_rn(__fadd_rn(o2, cd.z), dn);
                            int   j  = __float_as_int(cd.w);
                            bool better = (d2 < best) || (d2 == best && j < bj);
                            best = better ? d2 : best;
                            bj   = better ? j  : bj;
                        }
                    }
                }
            }
        }

        // back-projection: [nbx*z, nby*z, z, 1] @ inv_param[b, view][:, 0:3]
        float nbx = bnd[2 * bj];
        float nby = bnd[2 * bj + 1];
        float z   = proj_finez[pf];
        const float* ip = inv_param + (size_t)(b * Vv + view) * 16;
        float h0 = nbx * z, h1 = nby * z;
        float r0 = h0 * ip[0] + h1 * ip[4] + z * ip[8]  + ip[12];
        float r1 = h0 * ip[1] + h1 * ip[5] + z * ip[9]  + ip[13];
        float r2 = h0 * ip[2] + h1 * ip[6] + z * ip[10] + ip[14];
        out[ob]     = r0;
        out[ob + 1] = r1;
        out[ob + 2] = r2;
    } else {
        out[ob]     = pc[ob];
        out[ob + 1] = pc[ob + 1];
        out[ob + 2] = pc[ob + 2];
    }
}

extern "C" void kernel_launch(void* const* d_in, const int* in_sizes, int n_in,
                              void* d_out, int out_size, void* d_ws, size_t ws_size,
                              hipStream_t stream) {
    const float* pc         = (const float*)d_in[0];
    const float* mask       = (const float*)d_in[1];
    const float* bounds     = (const float*)d_in[2];
    const float* inv_param  = (const float*)d_in[3];
    const float* proj_fine  = (const float*)d_in[4];
    const float* proj_finez = (const float*)d_in[5];
    const int*   view_p     = (const int*)d_in[6];
    float* out = (float*)d_out;

    dim3 grid(Nn / 256, Bb);              // 512 blocks, one launch, no ws
    calib_kernel<<<grid, 256, 0, stream>>>(pc, mask, bounds, inv_param,
                                           proj_fine, proj_finez, view_p, out);
}

// Round 17
// 18.812 us; speedup vs baseline: 5.3223x; 1.0104x over previous
//
#include <hip/hip_runtime.h>
#include <math.h>

constexpr int IMG = 224;
constexpr int Bb  = 16;
constexpr int Vv  = 8;
constexpr int Nn  = 8192;
constexpr int Mm  = 1024;
constexpr int G   = 32;                 // bins per axis
constexpr float Hh = 1.0f / 32.0f;      // cell size, normalized coords

// Fused kernel, 256 blocks (1/CU) x 512 threads (8 waves/CU — same wave
// count as the 512x256 best config, but HALF the machine-wide binning
// redundancy: each batch is binned 16x instead of 32x).
__global__ __launch_bounds__(512) void calib_kernel(
    const float* __restrict__ pc,         // (B, N, 3)
    const float* __restrict__ mask,       // (B, V, IMG, IMG)
    const float* __restrict__ bounds,     // (B, V, M, 2)
    const float* __restrict__ inv_param,  // (B, V, 4, 4)
    const float* __restrict__ proj_fine,  // (B, V, N, 2)
    const float* __restrict__ proj_finez, // (B, V, N)
    const int*   __restrict__ view_p,
    float*       __restrict__ out)        // (B, N, 3)
{
    const int view = *view_p;
    const int b = blockIdx.y;
    const int t = threadIdx.x;
    const int lane = t & 63;
    const int w = t >> 6;                 // wave id, 0..7

    __shared__ float4 s_e[Mm];            // packed (bdx, bdy, |bd|^2, j)
    __shared__ int s_start[1025];         // cell -> range start
    __shared__ int s_cnt[1024];           // counts, then cursors
    __shared__ int s_wtot[8];

    // ---------------- phase 1: bin this batch's candidates ----------------
    #pragma unroll
    for (int u = 0; u < 2; ++u) s_cnt[t + 512 * u] = 0;
    __syncthreads();

    const float* bnd = bounds + (size_t)(b * Vv + view) * Mm * 2;
    float bdx[2], bdy[2];
    int cell[2];
    #pragma unroll
    for (int u = 0; u < 2; ++u) {
        int j = t + 512 * u;
        float2 bxy = reinterpret_cast<const float2*>(bnd)[j];
        bdx[u] = bxy.x / (float)IMG;      // exact IEEE div, matches ref
        bdy[u] = bxy.y / (float)IMG;
        int cx = min(G - 1, max(0, (int)(bdx[u] * (float)G)));
        int cy = min(G - 1, max(0, (int)(bdy[u] * (float)G)));
        cell[u] = cy * G + cx;
        atomicAdd(&s_cnt[cell[u]], 1);
    }
    __syncthreads();

    // prefix sum over 1024 cells: 2 serial/thread + wave shfl-scan + fixup
    int c0 = s_cnt[2 * t], c1 = s_cnt[2 * t + 1];
    int psum = c0 + c1;
    int incl = psum;
    #pragma unroll
    for (int off = 1; off < 64; off <<= 1) {
        int v = __shfl_up(incl, off);
        if (lane >= off) incl += v;
    }
    if (lane == 63) s_wtot[w] = incl;
    __syncthreads();
    int basew = 0;
    #pragma unroll
    for (int ww = 0; ww < 8; ++ww) basew += (ww < w) ? s_wtot[ww] : 0;
    int base = basew + incl - psum;       // exclusive start of cell 2t
    s_start[2 * t] = base;
    s_start[2 * t + 1] = base + c0;
    if (t == 0) s_start[1024] = Mm;
    s_cnt[2 * t] = base;
    s_cnt[2 * t + 1] = base + c0;
    __syncthreads();

    // scatter (intra-cell order atomic-arbitrary; lex (d2,j) reduction makes
    // the final result order-invariant => deterministic output)
    #pragma unroll
    for (int u = 0; u < 2; ++u) {
        int j = t + 512 * u;
        int pos = atomicAdd(&s_cnt[cell[u]], 1);
        float nrm = __fadd_rn(__fmul_rn(bdx[u], bdx[u]), __fmul_rn(bdy[u], bdy[u]));
        s_e[pos] = make_float4(bdx[u], bdy[u], nrm, __int_as_float(j));
    }
    __syncthreads();

    // ---------------- phase 2: one thread = one point ----------------------
    const int i = blockIdx.x * 512 + t;
    const size_t pf = (size_t)(b * Vv + view) * Nn + i;
    float2 pxy = reinterpret_cast<const float2*>(proj_fine)[pf];

    int i0 = (int)rintf(pxy.x);                 // round half-to-even
    int i1 = (int)rintf((float)IMG - pxy.y);

    // padded-mask probe
    int xi = min(max(i1 + 1, 0), IMG + 1);
    int yi = min(max(i0 + 1, 0), IMG + 1);
    float mval = 0.0f;
    if (xi >= 1 && xi <= IMG && yi >= 1 && yi <= IMG)
        mval = mask[((size_t)(b * Vv + view) * IMG + (xi - 1)) * IMG + (yi - 1)];
    const bool use_back = (mval == 0.0f);

    const size_t ob = ((size_t)b * Nn + i) * 3;
    if (use_back) {
        float ox = (float)i0 / (float)IMG;
        float oy = (float)i1 / (float)IMG;
        float o2 = __fadd_rn(__fmul_rn(ox, ox), __fmul_rn(oy, oy));
        // exact power-of-2 scale; d2 bits identical to prior rounds
        float n2ox = __fmul_rn(-2.0f, ox);
        float n2oy = __fmul_rn(-2.0f, oy);

        int cx = min(G - 1, max(0, (int)(ox * (float)G)));
        int cy = min(G - 1, max(0, (int)(oy * (float)G)));

        float best = INFINITY;
        int   bj   = 0;

        // tier 1: full 5x5 window, serial per thread (visit order irrelevant)
        int x0 = max(cx - 2, 0), x1 = min(cx + 2, G - 1);
        int y0 = max(cy - 2, 0), y1 = min(cy + 2, G - 1);
        for (int yy = y0; yy <= y1; ++yy) {
            int rowb = yy * G;
            int e0 = s_start[rowb + x0];
            int e1 = s_start[rowb + x1 + 1];
            for (int e = e0; e < e1; ++e) {
                float4 cd = s_e[e];
                float dn = __fadd_rn(__fmul_rn(n2ox, cd.x), __fmul_rn(n2oy, cd.y));
                float d2 = __fadd_rn(__fadd_rn(o2, cd.z), dn);
                int   j  = __float_as_int(cd.w);
                bool better = (d2 < best) || (d2 == best && j < bj);
                best = better ? d2 : best;
                bj   = better ? j  : bj;
            }
        }

        // tier 2 (P~3e-6): serial ring walker, rings >= 3.
        // unvisited = Chebyshev cell-ring >= 3 => d >= 2h => d2 >= 4h^2-slop
        if (!(best < 4.0f * Hh * Hh - 1e-5f)) {
            for (int r = 3; r <= G; ++r) {
                float lim = (float)(r - 1) * Hh;
                if (best < lim * lim - 1e-5f) break;
                int rx0 = max(0, cx - r), rx1 = min(G - 1, cx + r);
                int ry0 = max(0, cy - r), ry1 = min(G - 1, cy + r);
                for (int yy = ry0; yy <= ry1; ++yy) {
                    bool yedge = (yy == cy - r) || (yy == cy + r);
                    for (int xx = rx0; xx <= rx1; ++xx) {
                        if (!yedge && xx != cx - r && xx != cx + r) continue;
                        int c = yy * G + xx;
                        int e0 = s_start[c], e1 = s_start[c + 1];
                        for (int e = e0; e < e1; ++e) {
                            float4 cd = s_e[e];
                            float dn = __fadd_rn(__fmul_rn(n2ox, cd.x), __fmul_rn(n2oy, cd.y));
                            float d2 = __fadd_rn(__fadd_rn(o2, cd.z), dn);
                            int   j  = __float_as_int(cd.w);
                            bool better = (d2 < best) || (d2 == best && j < bj);
                            best = better ? d2 : best;
                            bj   = better ? j  : bj;
                        }
                    }
                }
            }
        }

        // back-projection: [nbx*z, nby*z, z, 1] @ inv_param[b, view][:, 0:3]
        float nbx = bnd[2 * bj];
        float nby = bnd[2 * bj + 1];
        float z   = proj_finez[pf];
        const float* ip = inv_param + (size_t)(b * Vv + view) * 16;
        float h0 = nbx * z, h1 = nby * z;
        float r0 = h0 * ip[0] + h1 * ip[4] + z * ip[8]  + ip[12];
        float r1 = h0 * ip[1] + h1 * ip[5] + z * ip[9]  + ip[13];
        float r2 = h0 * ip[2] + h1 * ip[6] + z * ip[10] + ip[14];
        out[ob]     = r0;
        out[ob + 1] = r1;
        out[ob + 2] = r2;
    } else {
        out[ob]     = pc[ob];
        out[ob + 1] = pc[ob + 1];
        out[ob + 2] = pc[ob + 2];
    }
}

extern "C" void kernel_launch(void* const* d_in, const int* in_sizes, int n_in,
                              void* d_out, int out_size, void* d_ws, size_t ws_size,
                              hipStream_t stream) {
    const float* pc         = (const float*)d_in[0];
    const float* mask       = (const float*)d_in[1];
    const float* bounds     = (const float*)d_in[2];
    const float* inv_param  = (const float*)d_in[3];
    const float* proj_fine  = (const float*)d_in[4];
    const float* proj_finez = (const float*)d_in[5];
    const int*   view_p     = (const int*)d_in[6];
    float* out = (float*)d_out;

    dim3 grid(Nn / 512, Bb);              // 256 blocks = 1/CU, one launch
    calib_kernel<<<grid, 512, 0, stream>>>(pc, mask, bounds, inv_param,
                                           proj_fine, proj_finez, view_p, out);
}

// Round 18
// 18.466 us; speedup vs baseline: 5.4220x; 1.0187x over previous
//
#include <hip/hip_runtime.h>
#include <math.h>

constexpr int IMG = 224;
constexpr int Bb  = 16;
constexpr int Vv  = 8;
constexpr int Nn  = 8192;
constexpr int Mm  = 1024;
constexpr int G   = 32;                 // bins per axis
constexpr float Hh = 1.0f / 32.0f;      // cell size, normalized coords

// Fused kernel, 256 blocks (1/CU) x 512 threads. R17 structure plus:
// (a) all per-point global loads issued at kernel entry (hide under binning),
// (b) mask probe issued pre-barrier,
// (c) raw bounds mirrored into LDS so the epilogue's bnd[2*bj] dependent
//     global gather becomes an LDS read.
__global__ __launch_bounds__(512) void calib_kernel(
    const float* __restrict__ pc,         // (B, N, 3)
    const float* __restrict__ mask,       // (B, V, IMG, IMG)
    const float* __restrict__ bounds,     // (B, V, M, 2)
    const float* __restrict__ inv_param,  // (B, V, 4, 4)
    const float* __restrict__ proj_fine,  // (B, V, N, 2)
    const float* __restrict__ proj_finez, // (B, V, N)
    const int*   __restrict__ view_p,
    float*       __restrict__ out)        // (B, N, 3)
{
    const int view = *view_p;
    const int b = blockIdx.y;
    const int t = threadIdx.x;
    const int lane = t & 63;
    const int w = t >> 6;                 // wave id, 0..7

    __shared__ float4 s_e[Mm];            // packed (bdx, bdy, |bd|^2, j)  16 KB
    __shared__ float2 s_raw[Mm];          // raw (bx, by) by candidate j    8 KB
    __shared__ int s_start[1025];         // cell -> range start
    __shared__ int s_cnt[1024];           // counts, then cursors
    __shared__ int s_wtot[8];

    // ---- early-issue ALL per-point global loads (hide under binning) -----
    const int i = blockIdx.x * 512 + t;
    const size_t pf = (size_t)(b * Vv + view) * Nn + i;
    float2 pxy = reinterpret_cast<const float2*>(proj_fine)[pf];
    float z    = proj_finez[pf];
    const size_t ob = ((size_t)b * Nn + i) * 3;
    float pc0 = pc[ob], pc1 = pc[ob + 1], pc2 = pc[ob + 2];

    // ---------------- phase 1: bin this batch's candidates ----------------
    #pragma unroll
    for (int u = 0; u < 2; ++u) s_cnt[t + 512 * u] = 0;
    __syncthreads();

    const float* bnd = bounds + (size_t)(b * Vv + view) * Mm * 2;
    float bdx[2], bdy[2];
    int cell[2];
    #pragma unroll
    for (int u = 0; u < 2; ++u) {
        int j = t + 512 * u;
        float2 bxy = reinterpret_cast<const float2*>(bnd)[j];
        s_raw[j] = bxy;                   // raw mirror (exact loaded bits)
        bdx[u] = bxy.x / (float)IMG;      // exact IEEE div, matches ref
        bdy[u] = bxy.y / (float)IMG;
        int cx = min(G - 1, max(0, (int)(bdx[u] * (float)G)));
        int cy = min(G - 1, max(0, (int)(bdy[u] * (float)G)));
        cell[u] = cy * G + cx;
        atomicAdd(&s_cnt[cell[u]], 1);
    }

    // mask probe between hist and barrier: pxy has arrived; the probe's
    // latency hides under scan + scatter
    int i0 = (int)rintf(pxy.x);                 // round half-to-even
    int i1 = (int)rintf((float)IMG - pxy.y);
    int xi = min(max(i1 + 1, 0), IMG + 1);
    int yi = min(max(i0 + 1, 0), IMG + 1);
    float mval = 0.0f;
    if (xi >= 1 && xi <= IMG && yi >= 1 && yi <= IMG)
        mval = mask[((size_t)(b * Vv + view) * IMG + (xi - 1)) * IMG + (yi - 1)];
    const bool use_back = (mval == 0.0f);
    __syncthreads();

    // prefix sum over 1024 cells: 2 serial/thread + wave shfl-scan + fixup
    int c0 = s_cnt[2 * t], c1 = s_cnt[2 * t + 1];
    int psum = c0 + c1;
    int incl = psum;
    #pragma unroll
    for (int off = 1; off < 64; off <<= 1) {
        int v = __shfl_up(incl, off);
        if (lane >= off) incl += v;
    }
    if (lane == 63) s_wtot[w] = incl;
    __syncthreads();
    int basew = 0;
    #pragma unroll
    for (int ww = 0; ww < 8; ++ww) basew += (ww < w) ? s_wtot[ww] : 0;
    int base = basew + incl - psum;       // exclusive start of cell 2t
    s_start[2 * t] = base;
    s_start[2 * t + 1] = base + c0;
    if (t == 0) s_start[1024] = Mm;
    s_cnt[2 * t] = base;
    s_cnt[2 * t + 1] = base + c0;
    __syncthreads();

    // scatter (intra-cell order atomic-arbitrary; lex (d2,j) reduction makes
    // the final result order-invariant => deterministic output)
    #pragma unroll
    for (int u = 0; u < 2; ++u) {
        int j = t + 512 * u;
        int pos = atomicAdd(&s_cnt[cell[u]], 1);
        float nrm = __fadd_rn(__fmul_rn(bdx[u], bdx[u]), __fmul_rn(bdy[u], bdy[u]));
        s_e[pos] = make_float4(bdx[u], bdy[u], nrm, __int_as_float(j));
    }
    __syncthreads();

    // ---------------- phase 2: one thread = one point ----------------------
    if (use_back) {
        float ox = (float)i0 / (float)IMG;
        float oy = (float)i1 / (float)IMG;
        float o2 = __fadd_rn(__fmul_rn(ox, ox), __fmul_rn(oy, oy));
        // exact power-of-2 scale; d2 bits identical to prior rounds
        float n2ox = __fmul_rn(-2.0f, ox);
        float n2oy = __fmul_rn(-2.0f, oy);

        int cx = min(G - 1, max(0, (int)(ox * (float)G)));
        int cy = min(G - 1, max(0, (int)(oy * (float)G)));

        float best = INFINITY;
        int   bj   = 0;

        // tier 1: full 5x5 window, serial per thread (visit order irrelevant)
        int x0 = max(cx - 2, 0), x1 = min(cx + 2, G - 1);
        int y0 = max(cy - 2, 0), y1 = min(cy + 2, G - 1);
        for (int yy = y0; yy <= y1; ++yy) {
            int rowb = yy * G;
            int e0 = s_start[rowb + x0];
            int e1 = s_start[rowb + x1 + 1];
            for (int e = e0; e < e1; ++e) {
                float4 cd = s_e[e];
                float dn = __fadd_rn(__fmul_rn(n2ox, cd.x), __fmul_rn(n2oy, cd.y));
                float d2 = __fadd_rn(__fadd_rn(o2, cd.z), dn);
                int   j  = __float_as_int(cd.w);
                bool better = (d2 < best) || (d2 == best && j < bj);
                best = better ? d2 : best;
                bj   = better ? j  : bj;
            }
        }

        // tier 2 (P~3e-6): serial ring walker, rings >= 3.
        // unvisited = Chebyshev cell-ring >= 3 => d >= 2h => d2 >= 4h^2-slop
        if (!(best < 4.0f * Hh * Hh - 1e-5f)) {
            for (int r = 3; r <= G; ++r) {
                float lim = (float)(r - 1) * Hh;
                if (best < lim * lim - 1e-5f) break;
                int rx0 = max(0, cx - r), rx1 = min(G - 1, cx + r);
                int ry0 = max(0, cy - r), ry1 = min(G - 1, cy + r);
                for (int yy = ry0; yy <= ry1; ++yy) {
                    bool yedge = (yy == cy - r) || (yy == cy + r);
                    for (int xx = rx0; xx <= rx1; ++xx) {
                        if (!yedge && xx != cx - r && xx != cx + r) continue;
                        int c = yy * G + xx;
                        int e0 = s_start[c], e1 = s_start[c + 1];
                        for (int e = e0; e < e1; ++e) {
                            float4 cd = s_e[e];
                            float dn = __fadd_rn(__fmul_rn(n2ox, cd.x), __fmul_rn(n2oy, cd.y));
                            float d2 = __fadd_rn(__fadd_rn(o2, cd.z), dn);
                            int   j  = __float_as_int(cd.w);
                            bool better = (d2 < best) || (d2 == best && j < bj);
                            best = better ? d2 : best;
                            bj   = better ? j  : bj;
                        }
                    }
                }
            }
        }

        // back-projection using the LDS raw mirror (same bits as bnd[2*bj])
        float2 nb = s_raw[bj];
        const float* ip = inv_param + (size_t)(b * Vv + view) * 16;
        float h0 = nb.x * z, h1 = nb.y * z;
        float r0 = h0 * ip[0] + h1 * ip[4] + z * ip[8]  + ip[12];
        float r1 = h0 * ip[1] + h1 * ip[5] + z * ip[9]  + ip[13];
        float r2 = h0 * ip[2] + h1 * ip[6] + z * ip[10] + ip[14];
        out[ob]     = r0;
        out[ob + 1] = r1;
        out[ob + 2] = r2;
    } else {
        out[ob]     = pc0;
        out[ob + 1] = pc1;
        out[ob + 2] = pc2;
    }
}

extern "C" void kernel_launch(void* const* d_in, const int* in_sizes, int n_in,
                              void* d_out, int out_size, void* d_ws, size_t ws_size,
                              hipStream_t stream) {
    const float* pc         = (const float*)d_in[0];
    const float* mask       = (const float*)d_in[1];
    const float* bounds     = (const float*)d_in[2];
    const float* inv_param  = (const float*)d_in[3];
    const float* proj_fine  = (const float*)d_in[4];
    const float* proj_finez = (const float*)d_in[5];
    const int*   view_p     = (const int*)d_in[6];
    float* out = (float*)d_out;

    dim3 grid(Nn / 512, Bb);              // 256 blocks = 1/CU, one launch
    calib_kernel<<<grid, 512, 0, stream>>>(pc, mask, bounds, inv_param,
                                           proj_fine, proj_finez, view_p, out);
}